// Round 9
// baseline (207.067 us; speedup 1.0000x reference)
//
#include <hip/hip_runtime.h>
#include <hip/hip_fp16.h>

#define WIN 30
#define H1 500
#define H1P 512
#define H2 20
#define OUTD 4
#define CS 4            // column splits per graph in gemm
#define NBIN 49152      // histogram bins per range (u8-packed in LDS)
#define NBINW (NBIN/4)  // 12288 u32 words = 48KB LDS
#define NCH 48          // edge chunks for k_hist
#define RPB 512         // dst rows per bucket (power of two)
#define MAXPB 9216      // max edges per bucket (mean 8186, sd ~90; +11 sigma)
#define BINCHUNK 16384  // edges per k_bin block
#define NBMAX 400       // LDS array bound in k_bin (NB = 391)

typedef _Float16 f16x8 __attribute__((ext_vector_type(8)));
typedef float f32x4 __attribute__((ext_vector_type(4)));

// --- K1: partial histograms of src (out-degree), u8-packed LDS bins --------
__global__ __launch_bounds__(512) void k_hist(const int* __restrict__ src,
                                              unsigned* __restrict__ partial,
                                              int E) {
    __shared__ unsigned h[NBINW];
    const int tid = threadIdx.x;
    const int r = blockIdx.x / NCH, c = blockIdx.x % NCH;
    const int base = r * NBIN;
    for (int j = tid; j < NBINW; j += 512) h[j] = 0;
    __syncthreads();
    const int ce = ((E + NCH - 1) / NCH + 3) & ~3;
    const int start = c * ce;
    const int end = min(E, start + ce);
    for (int i = start + tid * 4; i < end; i += 512 * 4) {
        if (i + 3 < end) {
            int4 s4 = *(const int4*)(src + i);
            unsigned d;
            d = (unsigned)(s4.x - base); if (d < NBIN) atomicAdd(&h[d >> 2], 1u << ((d & 3) * 8));
            d = (unsigned)(s4.y - base); if (d < NBIN) atomicAdd(&h[d >> 2], 1u << ((d & 3) * 8));
            d = (unsigned)(s4.z - base); if (d < NBIN) atomicAdd(&h[d >> 2], 1u << ((d & 3) * 8));
            d = (unsigned)(s4.w - base); if (d < NBIN) atomicAdd(&h[d >> 2], 1u << ((d & 3) * 8));
        } else {
            for (int k = i; k < end; ++k) {
                unsigned d = (unsigned)(src[k] - base);
                if (d < NBIN) atomicAdd(&h[d >> 2], 1u << ((d & 3) * 8));
            }
        }
    }
    __syncthreads();
    unsigned* outp = partial + (size_t)blockIdx.x * NBINW;
    for (int j = tid; j < NBINW; j += 512) outp[j] = h[j];
}

// --- K2: merge partials -> degO --------------------------------------------
__global__ __launch_bounds__(256) void k_merge(const unsigned* __restrict__ partial,
                                               int* __restrict__ degO, int N, int nr) {
    int w = blockIdx.x * 256 + threadIdx.x;
    if (w >= nr * NBINW) return;
    int r = w / NBINW, lw = w - r * NBINW;
    const unsigned* p = partial + (size_t)(r * NCH) * NBINW + lw;
    unsigned b0 = 0, b1 = 0, b2 = 0, b3 = 0;
    for (int c = 0; c < NCH; ++c) {
        unsigned v = p[(size_t)c * NBINW];
        b0 += v & 0xFFu; b1 += (v >> 8) & 0xFFu;
        b2 += (v >> 16) & 0xFFu; b3 += v >> 24;
    }
    int n0 = r * NBIN + 4 * lw;
    if (n0 + 3 < N) {
        *(int4*)(degO + n0) = make_int4((int)b0, (int)b1, (int)b2, (int)b3);
    } else if (n0 < N) {
        degO[n0] = (int)b0;
        if (n0 + 1 < N) degO[n0 + 1] = (int)b1;
        if (n0 + 2 < N) degO[n0 + 2] = (int)b2;
    }
}

// --- K3: pre-scaled fp16 feature table, 64B rows; cols 30/31 zero ----------
__global__ __launch_bounds__(256) void k_prep(const float* __restrict__ feat,
                                              const int* __restrict__ degO,
                                              __half* __restrict__ xh, int N32) {
    int i = blockIdx.x * 256 + threadIdx.x;
    if (i < N32) {
        int n = i >> 5, d = i & 31;
        float v = 0.f;
        if (d < WIN) v = feat[(size_t)n * WIN + d] * rsqrtf((float)max(degO[n], 1));
        xh[i] = __float2half(v);
    }
}

// --- K4: W1 packed column-major fp16 [512][32] (zero-padded rows 30/31) ----
__global__ __launch_bounds__(256) void k_w1prep(const float* __restrict__ W1,
                                                __half* __restrict__ w1cm) {
    int i = blockIdx.x * 256 + threadIdx.x;  // i < 512*32
    int c = i >> 5, k = i & 31;
    float v = (k < WIN && c < H1) ? W1[k * H1 + c] : 0.f;
    w1cm[i] = __float2half(v);
}

// --- K5: bin edges by 512-node dst bucket; payload = (src<<9)|local_dst ----
// gcur[j] holds the running COUNT for bucket j (zeroed before launch).
__global__ __launch_bounds__(256) void k_bin(const int* __restrict__ src,
                                             const int* __restrict__ dst,
                                             int* __restrict__ gcur,
                                             unsigned* __restrict__ ebuf,
                                             int E, int NB) {
    __shared__ int cnt[NBMAX];
    __shared__ int base[NBMAX];
    const int tid = threadIdx.x;
    for (int j = tid; j < NB; j += 256) cnt[j] = 0;
    __syncthreads();
    const int start = blockIdx.x * BINCHUNK;
    const int end = min(E, start + BINCHUNK);
    for (int i = start + tid; i < end; i += 256)
        atomicAdd(&cnt[dst[i] >> 9], 1);
    __syncthreads();
    for (int j = tid; j < NB; j += 256) {
        int c = cnt[j];
        base[j] = j * MAXPB + (c ? atomicAdd(&gcur[j], c) : 0);
        cnt[j] = 0;  // reused as local cursor
    }
    __syncthreads();
    for (int i = start + tid; i < end; i += 256) {
        int d = dst[i];
        int b = d >> 9;
        int idx = atomicAdd(&cnt[b], 1);
        int pos = base[b] + idx;
        if (pos < (b + 1) * MAXPB)  // safety clamp (statistically never hit)
            ebuf[pos] = ((unsigned)src[i] << 9) | (unsigned)(d & 511);
    }
}

// --- K6: per-bucket aggregation: 2-pass LDS counting sort + reg accumulate -
// Thread task: node = task>>2 (0..511), col-chunk = (task&3)*8.
__global__ __launch_bounds__(256) void k_agg(const __half* __restrict__ xh,
                                             const unsigned* __restrict__ ebuf,
                                             const int* __restrict__ gcur,
                                             __half* __restrict__ agg, int N) {
    __shared__ unsigned es[MAXPB];   // 36KB: bucket edges sorted by local dst
    __shared__ int cnt[RPB + 1];     // run offsets (exclusive scan)
    __shared__ int cur[RPB];         // scatter cursors
    const int tid = threadIdx.x;
    const int b = blockIdx.x;
    for (int j = tid; j < RPB; j += 256) { cnt[j + 1] = 0; cur[j] = 0; }
    if (tid == 0) cnt[0] = 0;
    __syncthreads();
    const int ne = min(gcur[b], MAXPB);
    const unsigned* eb = ebuf + (size_t)b * MAXPB;
    // pass A: count local dst occupancy
    for (int i = tid; i < ne; i += 256)
        atomicAdd(&cnt[(int)(eb[i] & (RPB - 1)) + 1], 1);
    __syncthreads();
    // block scan of 512 counters: 8 serial per lane + 64-lane shfl scan
    if (tid < 64) {
        const int i0 = tid * 8;
        int s[8];
        int run = 0;
#pragma unroll
        for (int k = 0; k < 8; ++k) { run += cnt[i0 + k + 1]; s[k] = run; }
        int inc = run;
#pragma unroll
        for (int o = 1; o < 64; o <<= 1) {
            int u = __shfl_up(inc, o, 64);
            if (tid >= o) inc += u;
        }
        const int ex = inc - run;
#pragma unroll
        for (int k = 0; k < 8; ++k) cnt[i0 + k + 1] = ex + s[k];
    }
    __syncthreads();
    // pass B: re-read and scatter into sorted LDS order
    for (int i = tid; i < ne; i += 256) {
        unsigned p = eb[i];
        int ld = (int)(p & (RPB - 1));
        int idx = atomicAdd(&cur[ld], 1);
        es[cnt[ld] + idx] = p;
    }
    __syncthreads();
    // register accumulation over each node's contiguous run
    for (int task = tid; task < RPB * 4; task += 256) {
        const int node_l = task >> 2;
        const int c8 = (task & 3) * 8;
        const int o0 = cnt[node_l], o1 = cnt[node_l + 1];
        float a0 = 0.f, a1 = 0.f, a2 = 0.f, a3 = 0.f;
        float a4 = 0.f, a5 = 0.f, a6 = 0.f, a7 = 0.f;
        int j = o0;
#pragma unroll 2
        for (; j + 1 < o1; j += 2) {  // two independent gathers in flight
            unsigned p0 = es[j], p1 = es[j + 1];
            union { uint4 u4; __half2 h2[4]; } x0, x1;
            x0.u4 = *(const uint4*)(xh + (size_t)(p0 >> 9) * 32 + c8);
            x1.u4 = *(const uint4*)(xh + (size_t)(p1 >> 9) * 32 + c8);
            a0 += __low2float(x0.h2[0]) + __low2float(x1.h2[0]);
            a1 += __high2float(x0.h2[0]) + __high2float(x1.h2[0]);
            a2 += __low2float(x0.h2[1]) + __low2float(x1.h2[1]);
            a3 += __high2float(x0.h2[1]) + __high2float(x1.h2[1]);
            a4 += __low2float(x0.h2[2]) + __low2float(x1.h2[2]);
            a5 += __high2float(x0.h2[2]) + __high2float(x1.h2[2]);
            a6 += __low2float(x0.h2[3]) + __low2float(x1.h2[3]);
            a7 += __high2float(x0.h2[3]) + __high2float(x1.h2[3]);
        }
        if (j < o1) {
            unsigned p0 = es[j];
            union { uint4 u4; __half2 h2[4]; } x0;
            x0.u4 = *(const uint4*)(xh + (size_t)(p0 >> 9) * 32 + c8);
            a0 += __low2float(x0.h2[0]);  a1 += __high2float(x0.h2[0]);
            a2 += __low2float(x0.h2[1]);  a3 += __high2float(x0.h2[1]);
            a4 += __low2float(x0.h2[2]);  a5 += __high2float(x0.h2[2]);
            a6 += __low2float(x0.h2[3]);  a7 += __high2float(x0.h2[3]);
        }
        const int node = b * RPB + node_l;
        if (node < N) {
            float deg = (float)(o1 - o0);       // deg_in = run length (exact)
            float r = rsqrtf(fmaxf(deg, 1.f));
            union { uint4 u4; __half2 h2[4]; } y;
            y.h2[0] = __floats2half2_rn(a0 * r, a1 * r);
            y.h2[1] = __floats2half2_rn(a2 * r, a3 * r);
            y.h2[2] = __floats2half2_rn(a4 * r, a5 * r);
            y.h2[3] = __floats2half2_rn(a6 * r, a7 * r);
            *(uint4*)(agg + (size_t)node * 32 + c8) = y.u4;  // coalesced 16B
        }
    }
}

// --- K7: MFMA gemm + minmax pool + 2-exp silu ------------------------------
__global__ __launch_bounds__(256) void k_gemm(const __half* __restrict__ agg,
                                              const __half* __restrict__ w1cm,
                                              const float* __restrict__ b1,
                                              float* __restrict__ pooled,
                                              int NPG, int G) {
    const int bid = blockIdx.x;
    const int g = bid / CS, c = bid % CS;
    const int tid = threadIdx.x;
    const int w = tid >> 6;
    const int l = tid & 63;
    const int lo = l & 15, hi = l >> 4;

    f16x8 bfr[8];
#pragma unroll
    for (int ct = 0; ct < 8; ++ct) {
        int col = c * 128 + ct * 16 + lo;
        bfr[ct] = *(const f16x8*)(w1cm + (size_t)col * 32 + hi * 8);
    }
    float vmax[8], vmin[8];
#pragma unroll
    for (int ct = 0; ct < 8; ++ct) { vmax[ct] = -INFINITY; vmin[ct] = INFINITY; }

    const int mts = NPG >> 4;  // NPG divisible by 16
    for (int mt = w; mt < mts; mt += 4) {
        int node = g * NPG + mt * 16 + lo;
        f16x8 a = *(const f16x8*)(agg + (size_t)node * 32 + hi * 8);
#pragma unroll
        for (int ct = 0; ct < 8; ++ct) {
            f32x4 acc = {0.f, 0.f, 0.f, 0.f};
            acc = __builtin_amdgcn_mfma_f32_16x16x32_f16(a, bfr[ct], acc, 0, 0, 0);
#pragma unroll
            for (int q = 0; q < 4; ++q) {
                vmax[ct] = fmaxf(vmax[ct], acc[q]);
                vmin[ct] = fminf(vmin[ct], acc[q]);
            }
        }
    }
#pragma unroll
    for (int ct = 0; ct < 8; ++ct) {
        vmax[ct] = fmaxf(vmax[ct], __shfl_xor(vmax[ct], 16, 64));
        vmax[ct] = fmaxf(vmax[ct], __shfl_xor(vmax[ct], 32, 64));
        vmin[ct] = fminf(vmin[ct], __shfl_xor(vmin[ct], 16, 64));
        vmin[ct] = fminf(vmin[ct], __shfl_xor(vmin[ct], 32, 64));
    }
    __shared__ float red[2][4][8][16];
    if (hi == 0) {
#pragma unroll
        for (int ct = 0; ct < 8; ++ct) {
            red[0][w][ct][lo] = vmax[ct];
            red[1][w][ct][lo] = vmin[ct];
        }
    }
    __syncthreads();
    if (tid < 128) {
        int ct = tid >> 4, col16 = tid & 15;
        float m = fmaxf(fmaxf(red[0][0][ct][col16], red[0][1][ct][col16]),
                        fmaxf(red[0][2][ct][col16], red[0][3][ct][col16]));
        float n = fminf(fminf(red[1][0][ct][col16], red[1][1][ct][col16]),
                        fminf(red[1][2][ct][col16], red[1][3][ct][col16]));
        int col = c * 128 + ct * 16 + col16;
        float bb = (col < H1) ? b1[col] : 0.f;
        m += bb; n += bb;
        float sm = m / (1.f + __expf(-m));
        float sn = n / (1.f + __expf(-n));
        pooled[(size_t)g * H1P + col] = fmaxf(sm, sn);
    }
}

// --- K8: tiny head ---------------------------------------------------------
__global__ __launch_bounds__(64) void k_head(const float* __restrict__ pooled,
                                             const float* __restrict__ W2,
                                             const float* __restrict__ b2,
                                             const float* __restrict__ W3,
                                             const float* __restrict__ b3,
                                             float* __restrict__ out, int G) {
    const int g = blockIdx.x;
    const int t = threadIdx.x;
    __shared__ float y[H2];
    if (t < H2) {
        float acc = b2[t];
        for (int k = 0; k < H1; ++k)
            acc = fmaf(pooled[(size_t)g * H1P + k], W2[k * H2 + t], acc);
        y[t] = acc / (1.f + __expf(-acc));
    }
    __syncthreads();
    if (t < OUTD) {
        float acc = b3[t];
#pragma unroll
        for (int k = 0; k < H2; ++k) acc = fmaf(y[k], W3[k * OUTD + t], acc);
        out[g * OUTD + t] = 1.f / (1.f + __expf(-acc));
    }
}

static inline size_t align256(size_t x) { return (x + 255) & ~(size_t)255; }

extern "C" void kernel_launch(void* const* d_in, const int* in_sizes, int n_in,
                              void* d_out, int out_size, void* d_ws, size_t ws_size,
                              hipStream_t stream) {
    const float* feat = (const float*)d_in[0];
    const int*   src  = (const int*)d_in[1];
    const int*   dst  = (const int*)d_in[2];
    const float* W1 = (const float*)d_in[5];
    const float* b1 = (const float*)d_in[6];
    const float* W2 = (const float*)d_in[7];
    const float* b2 = (const float*)d_in[8];
    const float* W3 = (const float*)d_in[9];
    const float* b3 = (const float*)d_in[10];
    float* out = (float*)d_out;

    const int N = in_sizes[0] / WIN;
    const int E = in_sizes[1];
    const int G = out_size / OUTD;
    const int NPG = N / G;                 // 2000; divisible by 16
    const int nr = (N + NBIN - 1) / NBIN;  // 5 ranges
    const int NB = (N + RPB - 1) / RPB;    // 391 buckets (<= NBMAX)

    // layout: [degO | partial | xh | w1cm | pooled | agg | gcur | ebuf]
    char* ws = (char*)d_ws;
    size_t off = 0;
    int*      degO    = (int*)(ws + off);      off += align256((size_t)N * 4);
    unsigned* partial = (unsigned*)(ws + off); off += align256((size_t)nr * NCH * NBINW * 4);
    __half*   xh      = (__half*)(ws + off);   off += align256((size_t)N * 32 * 2);
    __half*   w1cm    = (__half*)(ws + off);   off += align256((size_t)H1P * 32 * 2);
    float*    pooled  = (float*)(ws + off);    off += align256((size_t)G * H1P * 4);
    __half*   agg     = (__half*)(ws + off);   off += align256((size_t)N * 32 * 2);
    int*      gcur    = (int*)(ws + off);      off += align256((size_t)NB * 4);
    unsigned* ebuf    = (unsigned*)(ws + off); off += align256((size_t)NB * MAXPB * 4 + 256);
    (void)ws_size; (void)n_in;

    hipMemsetAsync(gcur, 0, (size_t)NB * 4, stream);

    k_hist<<<nr * NCH, 512, 0, stream>>>(src, partial, E);
    k_merge<<<(nr * NBINW + 255) / 256, 256, 0, stream>>>(partial, degO, N, nr);
    k_w1prep<<<(H1P * 32) / 256, 256, 0, stream>>>(W1, w1cm);
    k_prep<<<(N * 32 + 255) / 256, 256, 0, stream>>>(feat, degO, xh, N * 32);

    k_bin<<<(E + BINCHUNK - 1) / BINCHUNK, 256, 0, stream>>>(src, dst, gcur, ebuf, E, NB);
    k_agg<<<NB, 256, 0, stream>>>(xh, ebuf, gcur, agg, N);

    k_gemm<<<G * CS, 256, 0, stream>>>(agg, w1cm, b1, pooled, NPG, G);
    k_head<<<G, 64, 0, stream>>>(pooled, W2, b2, W3, b3, out, G);
}

// Round 10
// 165.770 us; speedup vs baseline: 1.2491x; 1.2491x over previous
//
#include <hip/hip_runtime.h>
#include <hip/hip_fp16.h>

#define WIN 30
#define H1 500
#define H1P 512
#define H2 20
#define OUTD 4
#define CS 4            // column splits per graph in gemm
#define NBIN 49152      // histogram bins per range (u8-packed in LDS)
#define NBINW (NBIN/4)  // 12288 u32 words = 48KB LDS
#define NCH 48          // edge chunks for k_hist
#define RPB 512         // dst rows per bucket (power of two)
#define MAXPB 9216      // max edges per bucket (mean 8186, sd ~90; +11 sigma)
#define BINCHUNK 8192   // edges per k_bin block
#define NBMAX 400       // LDS array bound in k_bin (NB = 391)

typedef _Float16 f16x8 __attribute__((ext_vector_type(8)));
typedef float f32x4 __attribute__((ext_vector_type(4)));

// --- K1: partial histograms of src (out-degree), u8-packed LDS bins --------
__global__ __launch_bounds__(512) void k_hist(const int* __restrict__ src,
                                              unsigned* __restrict__ partial,
                                              int E) {
    __shared__ unsigned h[NBINW];
    const int tid = threadIdx.x;
    const int r = blockIdx.x / NCH, c = blockIdx.x % NCH;
    const int base = r * NBIN;
    for (int j = tid; j < NBINW; j += 512) h[j] = 0;
    __syncthreads();
    const int ce = ((E + NCH - 1) / NCH + 3) & ~3;
    const int start = c * ce;
    const int end = min(E, start + ce);
    for (int i = start + tid * 4; i < end; i += 512 * 4) {
        if (i + 3 < end) {
            int4 s4 = *(const int4*)(src + i);
            unsigned d;
            d = (unsigned)(s4.x - base); if (d < NBIN) atomicAdd(&h[d >> 2], 1u << ((d & 3) * 8));
            d = (unsigned)(s4.y - base); if (d < NBIN) atomicAdd(&h[d >> 2], 1u << ((d & 3) * 8));
            d = (unsigned)(s4.z - base); if (d < NBIN) atomicAdd(&h[d >> 2], 1u << ((d & 3) * 8));
            d = (unsigned)(s4.w - base); if (d < NBIN) atomicAdd(&h[d >> 2], 1u << ((d & 3) * 8));
        } else {
            for (int k = i; k < end; ++k) {
                unsigned d = (unsigned)(src[k] - base);
                if (d < NBIN) atomicAdd(&h[d >> 2], 1u << ((d & 3) * 8));
            }
        }
    }
    __syncthreads();
    unsigned* outp = partial + (size_t)blockIdx.x * NBINW;
    for (int j = tid; j < NBINW; j += 512) outp[j] = h[j];
}

// --- K2: merge partials -> degO --------------------------------------------
__global__ __launch_bounds__(256) void k_merge(const unsigned* __restrict__ partial,
                                               int* __restrict__ degO, int N, int nr) {
    int w = blockIdx.x * 256 + threadIdx.x;
    if (w >= nr * NBINW) return;
    int r = w / NBINW, lw = w - r * NBINW;
    const unsigned* p = partial + (size_t)(r * NCH) * NBINW + lw;
    unsigned b0 = 0, b1 = 0, b2 = 0, b3 = 0;
    for (int c = 0; c < NCH; ++c) {
        unsigned v = p[(size_t)c * NBINW];
        b0 += v & 0xFFu; b1 += (v >> 8) & 0xFFu;
        b2 += (v >> 16) & 0xFFu; b3 += v >> 24;
    }
    int n0 = r * NBIN + 4 * lw;
    if (n0 + 3 < N) {
        *(int4*)(degO + n0) = make_int4((int)b0, (int)b1, (int)b2, (int)b3);
    } else if (n0 < N) {
        degO[n0] = (int)b0;
        if (n0 + 1 < N) degO[n0 + 1] = (int)b1;
        if (n0 + 2 < N) degO[n0 + 2] = (int)b2;
    }
}

// --- K3: pre-scaled fp16 feature table, 64B rows; cols 30/31 zero ----------
__global__ __launch_bounds__(256) void k_prep(const float* __restrict__ feat,
                                              const int* __restrict__ degO,
                                              __half* __restrict__ xh, int N32) {
    int i = blockIdx.x * 256 + threadIdx.x;
    if (i < N32) {
        int n = i >> 5, d = i & 31;
        float v = 0.f;
        if (d < WIN) v = feat[(size_t)n * WIN + d] * rsqrtf((float)max(degO[n], 1));
        xh[i] = __float2half(v);
    }
}

// --- K4: W1 packed column-major fp16 [512][32] (zero-padded rows 30/31) ----
__global__ __launch_bounds__(256) void k_w1prep(const float* __restrict__ W1,
                                                __half* __restrict__ w1cm) {
    int i = blockIdx.x * 256 + threadIdx.x;  // i < 512*32
    int c = i >> 5, k = i & 31;
    float v = (k < WIN && c < H1) ? W1[k * H1 + c] : 0.f;
    w1cm[i] = __float2half(v);
}

// --- K5: bin edges by 512-node dst bucket; payload = (src<<9)|local_dst ----
// gcur[j] holds the running COUNT for bucket j (zeroed before launch).
__global__ __launch_bounds__(1024) void k_bin(const int* __restrict__ src,
                                              const int* __restrict__ dst,
                                              int* __restrict__ gcur,
                                              unsigned* __restrict__ ebuf,
                                              int E, int NB) {
    __shared__ int cnt[NBMAX];
    __shared__ int base[NBMAX];
    const int tid = threadIdx.x;
    for (int j = tid; j < NB; j += 1024) cnt[j] = 0;
    __syncthreads();
    const int start = blockIdx.x * BINCHUNK;
    const int end = min(E, start + BINCHUNK);
    for (int i = start + tid; i < end; i += 1024)
        atomicAdd(&cnt[dst[i] >> 9], 1);
    __syncthreads();
    for (int j = tid; j < NB; j += 1024) {
        int c = cnt[j];
        base[j] = j * MAXPB + (c ? atomicAdd(&gcur[j], c) : 0);
        cnt[j] = 0;  // reused as local cursor
    }
    __syncthreads();
    for (int i = start + tid; i < end; i += 1024) {
        int d = dst[i];
        int b = d >> 9;
        int idx = atomicAdd(&cnt[b], 1);
        int pos = base[b] + idx;
        if (pos < (b + 1) * MAXPB)  // safety clamp (statistically never hit)
            ebuf[pos] = ((unsigned)src[i] << 9) | (unsigned)(d & 511);
    }
}

// --- K6: per-bucket aggregation: 2-pass LDS counting sort + reg accumulate -
// Thread task: node = task>>2 (0..511), col-chunk = (task&3)*8.
__global__ __launch_bounds__(1024) void k_agg(const __half* __restrict__ xh,
                                              const unsigned* __restrict__ ebuf,
                                              const int* __restrict__ gcur,
                                              __half* __restrict__ agg, int N) {
    __shared__ unsigned es[MAXPB];   // 36KB: bucket edges sorted by local dst
    __shared__ int cnt[RPB + 1];     // run offsets (exclusive scan)
    __shared__ int cur[RPB];         // scatter cursors
    const int tid = threadIdx.x;
    const int b = blockIdx.x;
    for (int j = tid; j < RPB; j += 1024) { cnt[j + 1] = 0; cur[j] = 0; }
    if (tid == 0) cnt[0] = 0;
    __syncthreads();
    const int ne = min(gcur[b], MAXPB);
    const unsigned* eb = ebuf + (size_t)b * MAXPB;
    // pass A: count local dst occupancy
    for (int i = tid; i < ne; i += 1024)
        atomicAdd(&cnt[(int)(eb[i] & (RPB - 1)) + 1], 1);
    __syncthreads();
    // block scan of 512 counters: 8 serial per lane + 64-lane shfl scan
    if (tid < 64) {
        const int i0 = tid * 8;
        int s[8];
        int run = 0;
#pragma unroll
        for (int k = 0; k < 8; ++k) { run += cnt[i0 + k + 1]; s[k] = run; }
        int inc = run;
#pragma unroll
        for (int o = 1; o < 64; o <<= 1) {
            int u = __shfl_up(inc, o, 64);
            if (tid >= o) inc += u;
        }
        const int ex = inc - run;
#pragma unroll
        for (int k = 0; k < 8; ++k) cnt[i0 + k + 1] = ex + s[k];
    }
    __syncthreads();
    // pass B: re-read and scatter into sorted LDS order
    for (int i = tid; i < ne; i += 1024) {
        unsigned p = eb[i];
        int ld = (int)(p & (RPB - 1));
        int idx = atomicAdd(&cur[ld], 1);
        es[cnt[ld] + idx] = p;
    }
    __syncthreads();
    // register accumulation over each node's contiguous run
    for (int task = tid; task < RPB * 4; task += 1024) {
        const int node_l = task >> 2;
        const int c8 = (task & 3) * 8;
        const int o0 = cnt[node_l], o1 = cnt[node_l + 1];
        float a0 = 0.f, a1 = 0.f, a2 = 0.f, a3 = 0.f;
        float a4 = 0.f, a5 = 0.f, a6 = 0.f, a7 = 0.f;
        int j = o0;
#pragma unroll 2
        for (; j + 1 < o1; j += 2) {  // two independent gathers in flight
            unsigned p0 = es[j], p1 = es[j + 1];
            union { uint4 u4; __half2 h2[4]; } x0, x1;
            x0.u4 = *(const uint4*)(xh + (size_t)(p0 >> 9) * 32 + c8);
            x1.u4 = *(const uint4*)(xh + (size_t)(p1 >> 9) * 32 + c8);
            a0 += __low2float(x0.h2[0]) + __low2float(x1.h2[0]);
            a1 += __high2float(x0.h2[0]) + __high2float(x1.h2[0]);
            a2 += __low2float(x0.h2[1]) + __low2float(x1.h2[1]);
            a3 += __high2float(x0.h2[1]) + __high2float(x1.h2[1]);
            a4 += __low2float(x0.h2[2]) + __low2float(x1.h2[2]);
            a5 += __high2float(x0.h2[2]) + __high2float(x1.h2[2]);
            a6 += __low2float(x0.h2[3]) + __low2float(x1.h2[3]);
            a7 += __high2float(x0.h2[3]) + __high2float(x1.h2[3]);
        }
        if (j < o1) {
            unsigned p0 = es[j];
            union { uint4 u4; __half2 h2[4]; } x0;
            x0.u4 = *(const uint4*)(xh + (size_t)(p0 >> 9) * 32 + c8);
            a0 += __low2float(x0.h2[0]);  a1 += __high2float(x0.h2[0]);
            a2 += __low2float(x0.h2[1]);  a3 += __high2float(x0.h2[1]);
            a4 += __low2float(x0.h2[2]);  a5 += __high2float(x0.h2[2]);
            a6 += __low2float(x0.h2[3]);  a7 += __high2float(x0.h2[3]);
        }
        const int node = b * RPB + node_l;
        if (node < N) {
            float deg = (float)(o1 - o0);       // deg_in = run length (exact)
            float r = rsqrtf(fmaxf(deg, 1.f));
            union { uint4 u4; __half2 h2[4]; } y;
            y.h2[0] = __floats2half2_rn(a0 * r, a1 * r);
            y.h2[1] = __floats2half2_rn(a2 * r, a3 * r);
            y.h2[2] = __floats2half2_rn(a4 * r, a5 * r);
            y.h2[3] = __floats2half2_rn(a6 * r, a7 * r);
            *(uint4*)(agg + (size_t)node * 32 + c8) = y.u4;  // coalesced 16B
        }
    }
}

// --- K7: MFMA gemm + minmax pool + 2-exp silu ------------------------------
__global__ __launch_bounds__(256) void k_gemm(const __half* __restrict__ agg,
                                              const __half* __restrict__ w1cm,
                                              const float* __restrict__ b1,
                                              float* __restrict__ pooled,
                                              int NPG, int G) {
    const int bid = blockIdx.x;
    const int g = bid / CS, c = bid % CS;
    const int tid = threadIdx.x;
    const int w = tid >> 6;
    const int l = tid & 63;
    const int lo = l & 15, hi = l >> 4;

    f16x8 bfr[8];
#pragma unroll
    for (int ct = 0; ct < 8; ++ct) {
        int col = c * 128 + ct * 16 + lo;
        bfr[ct] = *(const f16x8*)(w1cm + (size_t)col * 32 + hi * 8);
    }
    float vmax[8], vmin[8];
#pragma unroll
    for (int ct = 0; ct < 8; ++ct) { vmax[ct] = -INFINITY; vmin[ct] = INFINITY; }

    const int mts = NPG >> 4;  // NPG divisible by 16
    for (int mt = w; mt < mts; mt += 4) {
        int node = g * NPG + mt * 16 + lo;
        f16x8 a = *(const f16x8*)(agg + (size_t)node * 32 + hi * 8);
#pragma unroll
        for (int ct = 0; ct < 8; ++ct) {
            f32x4 acc = {0.f, 0.f, 0.f, 0.f};
            acc = __builtin_amdgcn_mfma_f32_16x16x32_f16(a, bfr[ct], acc, 0, 0, 0);
#pragma unroll
            for (int q = 0; q < 4; ++q) {
                vmax[ct] = fmaxf(vmax[ct], acc[q]);
                vmin[ct] = fminf(vmin[ct], acc[q]);
            }
        }
    }
#pragma unroll
    for (int ct = 0; ct < 8; ++ct) {
        vmax[ct] = fmaxf(vmax[ct], __shfl_xor(vmax[ct], 16, 64));
        vmax[ct] = fmaxf(vmax[ct], __shfl_xor(vmax[ct], 32, 64));
        vmin[ct] = fminf(vmin[ct], __shfl_xor(vmin[ct], 16, 64));
        vmin[ct] = fminf(vmin[ct], __shfl_xor(vmin[ct], 32, 64));
    }
    __shared__ float red[2][4][8][16];
    if (hi == 0) {
#pragma unroll
        for (int ct = 0; ct < 8; ++ct) {
            red[0][w][ct][lo] = vmax[ct];
            red[1][w][ct][lo] = vmin[ct];
        }
    }
    __syncthreads();
    if (tid < 128) {
        int ct = tid >> 4, col16 = tid & 15;
        float m = fmaxf(fmaxf(red[0][0][ct][col16], red[0][1][ct][col16]),
                        fmaxf(red[0][2][ct][col16], red[0][3][ct][col16]));
        float n = fminf(fminf(red[1][0][ct][col16], red[1][1][ct][col16]),
                        fminf(red[1][2][ct][col16], red[1][3][ct][col16]));
        int col = c * 128 + ct * 16 + col16;
        float bb = (col < H1) ? b1[col] : 0.f;
        m += bb; n += bb;
        float sm = m / (1.f + __expf(-m));
        float sn = n / (1.f + __expf(-n));
        pooled[(size_t)g * H1P + col] = fmaxf(sm, sn);
    }
}

// --- K8: tiny head ---------------------------------------------------------
__global__ __launch_bounds__(64) void k_head(const float* __restrict__ pooled,
                                             const float* __restrict__ W2,
                                             const float* __restrict__ b2,
                                             const float* __restrict__ W3,
                                             const float* __restrict__ b3,
                                             float* __restrict__ out, int G) {
    const int g = blockIdx.x;
    const int t = threadIdx.x;
    __shared__ float y[H2];
    if (t < H2) {
        float acc = b2[t];
        for (int k = 0; k < H1; ++k)
            acc = fmaf(pooled[(size_t)g * H1P + k], W2[k * H2 + t], acc);
        y[t] = acc / (1.f + __expf(-acc));
    }
    __syncthreads();
    if (t < OUTD) {
        float acc = b3[t];
#pragma unroll
        for (int k = 0; k < H2; ++k) acc = fmaf(y[k], W3[k * OUTD + t], acc);
        out[g * OUTD + t] = 1.f / (1.f + __expf(-acc));
    }
}

static inline size_t align256(size_t x) { return (x + 255) & ~(size_t)255; }

extern "C" void kernel_launch(void* const* d_in, const int* in_sizes, int n_in,
                              void* d_out, int out_size, void* d_ws, size_t ws_size,
                              hipStream_t stream) {
    const float* feat = (const float*)d_in[0];
    const int*   src  = (const int*)d_in[1];
    const int*   dst  = (const int*)d_in[2];
    const float* W1 = (const float*)d_in[5];
    const float* b1 = (const float*)d_in[6];
    const float* W2 = (const float*)d_in[7];
    const float* b2 = (const float*)d_in[8];
    const float* W3 = (const float*)d_in[9];
    const float* b3 = (const float*)d_in[10];
    float* out = (float*)d_out;

    const int N = in_sizes[0] / WIN;
    const int E = in_sizes[1];
    const int G = out_size / OUTD;
    const int NPG = N / G;                 // 2000; divisible by 16
    const int nr = (N + NBIN - 1) / NBIN;  // 5 ranges
    const int NB = (N + RPB - 1) / RPB;    // 391 buckets (<= NBMAX)

    // layout: [degO | partial | xh | w1cm | pooled | agg | gcur | ebuf]
    char* ws = (char*)d_ws;
    size_t off = 0;
    int*      degO    = (int*)(ws + off);      off += align256((size_t)N * 4);
    unsigned* partial = (unsigned*)(ws + off); off += align256((size_t)nr * NCH * NBINW * 4);
    __half*   xh      = (__half*)(ws + off);   off += align256((size_t)N * 32 * 2);
    __half*   w1cm    = (__half*)(ws + off);   off += align256((size_t)H1P * 32 * 2);
    float*    pooled  = (float*)(ws + off);    off += align256((size_t)G * H1P * 4);
    __half*   agg     = (__half*)(ws + off);   off += align256((size_t)N * 32 * 2);
    int*      gcur    = (int*)(ws + off);      off += align256((size_t)NB * 4);
    unsigned* ebuf    = (unsigned*)(ws + off); off += align256((size_t)NB * MAXPB * 4 + 256);
    (void)ws_size; (void)n_in;

    hipMemsetAsync(gcur, 0, (size_t)NB * 4, stream);

    k_hist<<<nr * NCH, 512, 0, stream>>>(src, partial, E);
    k_merge<<<(nr * NBINW + 255) / 256, 256, 0, stream>>>(partial, degO, N, nr);
    k_w1prep<<<(H1P * 32) / 256, 256, 0, stream>>>(W1, w1cm);
    k_prep<<<(N * 32 + 255) / 256, 256, 0, stream>>>(feat, degO, xh, N * 32);

    k_bin<<<(E + BINCHUNK - 1) / BINCHUNK, 1024, 0, stream>>>(src, dst, gcur, ebuf, E, NB);
    k_agg<<<NB, 1024, 0, stream>>>(xh, ebuf, gcur, agg, N);

    k_gemm<<<G * CS, 256, 0, stream>>>(agg, w1cm, b1, pooled, NPG, G);
    k_head<<<G, 64, 0, stream>>>(pooled, W2, b2, W3, b3, out, G);
}